// Round 12
// baseline (103.158 us; speedup 1.0000x reference)
//
#include <hip/hip_runtime.h>
#include <math.h>

#define B 32
#define N 16384
#define DIM 64
#define HID 64
#define KD 16
#define DM 512
#define MP 16

#define GRID_SAL 2048   // 8 blocks/CU nominal (TLP for latency hiding)
#define ITERS 4         // 2048 * 4 * 64 rows = 524288 = B*N

typedef __attribute__((ext_vector_type(8))) _Float16 f16x8;
typedef __attribute__((ext_vector_type(2))) __fp16 fph2;   // cvt_pkrtz return type
typedef __attribute__((ext_vector_type(4))) float f32x4;

// tanh via exp + RAW v_rcp (no -ffast-math: '/' would emit the IEEE div sequence).
__device__ __forceinline__ float fast_tanh(float a) {
  const float e = __expf(2.f * a);
  return 1.f - 2.f * __builtin_amdgcn_rcpf(e + 1.f);
}

// ---------- Kernel 0: one-time W1 -> transposed fp16 hi/lo split (Wt[col][k]) ----------
__global__ __launch_bounds__(256) void k_prepw(
    const float* __restrict__ W1, _Float16* __restrict__ Wt_hi, _Float16* __restrict__ Wt_lo) {
  const int i = blockIdx.x * 256 + threadIdx.x;   // < 4096
  const int col = i >> 6, k = i & 63;
  const float v = W1[k * HID + col];
  const _Float16 h = (_Float16)v;
  Wt_hi[i] = h;
  Wt_lo[i] = (_Float16)(v - (float)h);
}

// ---------- Kernel 1: saliency, persistent + pipelined, fp16x3 MFMA, W in registers ----------
__global__ __launch_bounds__(256) void k_saliency(
    const float* __restrict__ x, const _Float16* __restrict__ Wt_hi,
    const _Float16* __restrict__ Wt_lo, const float* __restrict__ b1,
    const float* __restrict__ w_s, float* __restrict__ sal) {
  const int t = threadIdx.x;
  const int lane = t & 63, wid = t >> 6;
  const int c16 = lane & 15, kq = lane >> 4;
  const int wbase = c16 * 64 + kq * 8;            // Wt elem base for this lane

  // Hoist ALL W fragments: WH/WL[ct*2+kc], tile-invariant, 64 VGPR total.
  f16x8 WH[8], WL[8];
#pragma unroll
  for (int ct = 0; ct < 4; ++ct)
#pragma unroll
    for (int kc = 0; kc < 2; ++kc) {
      const int off = ct * 1024 + kc * 32 + wbase;
      WH[ct * 2 + kc] = *(const f16x8*)(Wt_hi + off);
      WL[ct * 2 + kc] = *(const f16x8*)(Wt_lo + off);
    }

#define PKSPLIT(va, vb, HW, LW) {                                                  \
    const fph2 h_ = __builtin_amdgcn_cvt_pkrtz((va), (vb));                        \
    const fph2 l_ = __builtin_amdgcn_cvt_pkrtz((va) - (float)h_[0],                \
                                               (vb) - (float)h_[1]);               \
    HW = __builtin_bit_cast(unsigned, h_);                                         \
    LW = __builtin_bit_cast(unsigned, l_); }

#define SAL_LOADS(b0, b1_, b2, b3, it_) {                                          \
    const size_t row_ = ((size_t)(it_) * GRID_SAL + blockIdx.x) * 64 + wid * 16 + c16; \
    const float* __restrict__ p_ = x + row_ * DIM + kq * 8;                        \
    b0 = *(const float4*)(p_);       b1_ = *(const float4*)(p_ + 4);               \
    b2 = *(const float4*)(p_ + 32);  b3 = *(const float4*)(p_ + 36); }

#define SAL_COMPUTE(b0, b1_, b2, b3, it_) {                                        \
    f32x4 a0 = (f32x4)0.f, a1 = (f32x4)0.f, a2 = (f32x4)0.f, a3 = (f32x4)0.f;      \
    { /* kc = 0 */                                                                 \
      uint4 H, L;                                                                  \
      PKSPLIT(b0.x, b0.y, H.x, L.x); PKSPLIT(b0.z, b0.w, H.y, L.y);                \
      PKSPLIT(b1_.x, b1_.y, H.z, L.z); PKSPLIT(b1_.z, b1_.w, H.w, L.w);            \
      const f16x8 bh = __builtin_bit_cast(f16x8, H);                               \
      const f16x8 bl = __builtin_bit_cast(f16x8, L);                               \
      a0 = __builtin_amdgcn_mfma_f32_16x16x32_f16(WH[0], bh, a0, 0, 0, 0);         \
      a1 = __builtin_amdgcn_mfma_f32_16x16x32_f16(WH[2], bh, a1, 0, 0, 0);         \
      a2 = __builtin_amdgcn_mfma_f32_16x16x32_f16(WH[4], bh, a2, 0, 0, 0);         \
      a3 = __builtin_amdgcn_mfma_f32_16x16x32_f16(WH[6], bh, a3, 0, 0, 0);         \
      a0 = __builtin_amdgcn_mfma_f32_16x16x32_f16(WL[0], bh, a0, 0, 0, 0);         \
      a1 = __builtin_amdgcn_mfma_f32_16x16x32_f16(WL[2], bh, a1, 0, 0, 0);         \
      a2 = __builtin_amdgcn_mfma_f32_16x16x32_f16(WL[4], bh, a2, 0, 0, 0);         \
      a3 = __builtin_amdgcn_mfma_f32_16x16x32_f16(WL[6], bh, a3, 0, 0, 0);         \
      a0 = __builtin_amdgcn_mfma_f32_16x16x32_f16(WH[0], bl, a0, 0, 0, 0);         \
      a1 = __builtin_amdgcn_mfma_f32_16x16x32_f16(WH[2], bl, a1, 0, 0, 0);         \
      a2 = __builtin_amdgcn_mfma_f32_16x16x32_f16(WH[4], bl, a2, 0, 0, 0);         \
      a3 = __builtin_amdgcn_mfma_f32_16x16x32_f16(WH[6], bl, a3, 0, 0, 0);         \
    }                                                                              \
    { /* kc = 1 */                                                                 \
      uint4 H, L;                                                                  \
      PKSPLIT(b2.x, b2.y, H.x, L.x); PKSPLIT(b2.z, b2.w, H.y, L.y);                \
      PKSPLIT(b3.x, b3.y, H.z, L.z); PKSPLIT(b3.z, b3.w, H.w, L.w);                \
      const f16x8 bh = __builtin_bit_cast(f16x8, H);                               \
      const f16x8 bl = __builtin_bit_cast(f16x8, L);                               \
      a0 = __builtin_amdgcn_mfma_f32_16x16x32_f16(WH[1], bh, a0, 0, 0, 0);         \
      a1 = __builtin_amdgcn_mfma_f32_16x16x32_f16(WH[3], bh, a1, 0, 0, 0);         \
      a2 = __builtin_amdgcn_mfma_f32_16x16x32_f16(WH[5], bh, a2, 0, 0, 0);         \
      a3 = __builtin_amdgcn_mfma_f32_16x16x32_f16(WH[7], bh, a3, 0, 0, 0);         \
      a0 = __builtin_amdgcn_mfma_f32_16x16x32_f16(WL[1], bh, a0, 0, 0, 0);         \
      a1 = __builtin_amdgcn_mfma_f32_16x16x32_f16(WL[3], bh, a1, 0, 0, 0);         \
      a2 = __builtin_amdgcn_mfma_f32_16x16x32_f16(WL[5], bh, a2, 0, 0, 0);         \
      a3 = __builtin_amdgcn_mfma_f32_16x16x32_f16(WL[7], bh, a3, 0, 0, 0);         \
      a0 = __builtin_amdgcn_mfma_f32_16x16x32_f16(WH[1], bl, a0, 0, 0, 0);         \
      a1 = __builtin_amdgcn_mfma_f32_16x16x32_f16(WH[3], bl, a1, 0, 0, 0);         \
      a2 = __builtin_amdgcn_mfma_f32_16x16x32_f16(WH[5], bl, a2, 0, 0, 0);         \
      a3 = __builtin_amdgcn_mfma_f32_16x16x32_f16(WH[7], bl, a3, 0, 0, 0);         \
    }                                                                              \
    float s = 0.f;                                                                 \
    { const f32x4 wv = *(const f32x4*)(w_s + kq * 4);                              \
      const f32x4 bv = *(const f32x4*)(b1 + kq * 4);                               \
      s = fmaf(wv[0], fast_tanh(a0[0] + bv[0]), s);                                \
      s = fmaf(wv[1], fast_tanh(a0[1] + bv[1]), s);                                \
      s = fmaf(wv[2], fast_tanh(a0[2] + bv[2]), s);                                \
      s = fmaf(wv[3], fast_tanh(a0[3] + bv[3]), s); }                              \
    { const f32x4 wv = *(const f32x4*)(w_s + 16 + kq * 4);                         \
      const f32x4 bv = *(const f32x4*)(b1 + 16 + kq * 4);                          \
      s = fmaf(wv[0], fast_tanh(a1[0] + bv[0]), s);                                \
      s = fmaf(wv[1], fast_tanh(a1[1] + bv[1]), s);                                \
      s = fmaf(wv[2], fast_tanh(a1[2] + bv[2]), s);                                \
      s = fmaf(wv[3], fast_tanh(a1[3] + bv[3]), s); }                              \
    { const f32x4 wv = *(const f32x4*)(w_s + 32 + kq * 4);                         \
      const f32x4 bv = *(const f32x4*)(b1 + 32 + kq * 4);                          \
      s = fmaf(wv[0], fast_tanh(a2[0] + bv[0]), s);                                \
      s = fmaf(wv[1], fast_tanh(a2[1] + bv[1]), s);                                \
      s = fmaf(wv[2], fast_tanh(a2[2] + bv[2]), s);                                \
      s = fmaf(wv[3], fast_tanh(a2[3] + bv[3]), s); }                              \
    { const f32x4 wv = *(const f32x4*)(w_s + 48 + kq * 4);                         \
      const f32x4 bv = *(const f32x4*)(b1 + 48 + kq * 4);                          \
      s = fmaf(wv[0], fast_tanh(a3[0] + bv[0]), s);                                \
      s = fmaf(wv[1], fast_tanh(a3[1] + bv[1]), s);                                \
      s = fmaf(wv[2], fast_tanh(a3[2] + bv[2]), s);                                \
      s = fmaf(wv[3], fast_tanh(a3[3] + bv[3]), s); }                              \
    s += __shfl_xor(s, 16);                                                        \
    s += __shfl_xor(s, 32);                                                        \
    if (lane < 16) {                                                               \
      const size_t sr_ = ((size_t)(it_) * GRID_SAL + blockIdx.x) * 64 + wid * 16 + lane; \
      const float z_ = __expf(-fabsf(s));                                          \
      sal[sr_] = fmaxf(s, 0.f) + __logf(1.f + z_);   /* softplus, no libm */       \
    } }

  float4 pA0, pA1, pA2, pA3;   // ping buffer
  float4 pB0, pB1, pB2, pB3;   // pong buffer

  SAL_LOADS(pA0, pA1, pA2, pA3, 0);
#pragma unroll 1
  for (int it2 = 0; it2 < ITERS; it2 += 2) {
    SAL_LOADS(pB0, pB1, pB2, pB3, it2 + 1);       // prefetch odd tile
    SAL_COMPUTE(pA0, pA1, pA2, pA3, it2);         // compute even tile
    if (it2 + 2 < ITERS) SAL_LOADS(pA0, pA1, pA2, pA3, it2 + 2);
    SAL_COMPUTE(pB0, pB1, pB2, pB3, it2 + 1);     // compute odd tile
  }
#undef SAL_LOADS
#undef SAL_COMPUTE
#undef PKSPLIT
}

// ---------- Kernel 2: per-row fused: stats + y_star + EXACT top-16 + lift + project ----------
// One 1024-thread block per row; row held in registers (16 f32/thread).
__global__ __launch_bounds__(1024) void k_rowtok(
    float* __restrict__ y,               // [B][N]: in = saliency, out = y_star
    const float* __restrict__ x,
    const float* __restrict__ W_lift, const float* __restrict__ b_lift,
    const float* __restrict__ W_proj, const float* __restrict__ b_proj,
    const float* __restrict__ mu, const float* __restrict__ sigma,
    float* __restrict__ tokens) {
  __shared__ float sb[16], ss[16], wvs[16];
  __shared__ int wis[16];
  __shared__ float s_val[MP];
  __shared__ int s_idx[MP];
  __shared__ float lifted[MP][KD + 1];
  const int b = blockIdx.x, t = threadIdx.x;
  const int wid = t >> 6, lane = t & 63;
  float* __restrict__ row = y + (size_t)b * N;

  float v[16];
#pragma unroll
  for (int j = 0; j < 16; ++j) v[j] = row[t + 1024 * j];

  // ---- row max ----
  float m = v[0];
#pragma unroll
  for (int j = 1; j < 16; ++j) m = fmaxf(m, v[j]);
#pragma unroll
  for (int off = 1; off < 64; off <<= 1) m = fmaxf(m, __shfl_xor(m, off));
  if (lane == 0) sb[wid] = m;
  __syncthreads();
  m = sb[0];
#pragma unroll
  for (int w = 1; w < 16; ++w) m = fmaxf(m, sb[w]);

  // ---- softmax denominator ----
  float se = 0.f;
#pragma unroll
  for (int j = 0; j < 16; ++j) se += __expf(v[j] - m);
#pragma unroll
  for (int off = 1; off < 64; off <<= 1) se += __shfl_xor(se, off);
  if (lane == 0) ss[wid] = se;
  __syncthreads();
  float S = ss[0];
#pragma unroll
  for (int w = 1; w < 16; ++w) S += ss[w];
  const float inv = __builtin_amdgcn_rcpf(S);

  // ---- y_star (before top-k deflation destroys v) ----
#pragma unroll
  for (int j = 0; j < 16; ++j) {
    const float sv = v[j];
    const float sig = __builtin_amdgcn_rcpf(1.f + __expf(-sv));
    row[t + 1024 * j] = fmaf(0.5f, sig, 4.f * __expf(sv - m) * inv);
  }

  // ---- exact top-16, (value desc, index asc); idx = t + 1024*j ----
  for (int k = 0; k < MP; ++k) {
    float bv = v[0]; int bj = 0;
#pragma unroll
    for (int j = 1; j < 16; ++j)
      if (v[j] > bv) { bv = v[j]; bj = j; }      // ascending j => smallest idx kept
    int bi = t + 1024 * bj;
#pragma unroll
    for (int off = 1; off < 64; off <<= 1) {
      const float ov = __shfl_xor(bv, off);
      const int   oi = __shfl_xor(bi, off);
      if (ov > bv || (ov == bv && oi < bi)) { bv = ov; bi = oi; }
    }
    if (lane == 0) { wvs[wid] = bv; wis[wid] = bi; }
    __syncthreads();
    float Bv = wvs[0]; int Bi = wis[0];
#pragma unroll
    for (int w = 1; w < 16; ++w)
      if (wvs[w] > Bv || (wvs[w] == Bv && wis[w] < Bi)) { Bv = wvs[w]; Bi = wis[w]; }
    if (t == 0) { s_val[k] = Bv; s_idx[k] = Bi; }
    // deflate winner (static indexing)
    const int rel = Bi - t;
#pragma unroll
    for (int jj = 0; jj < 16; ++jj)
      if (rel == 1024 * jj) v[jj] = -INFINITY;
    __syncthreads();
  }

  // ---- lift: first 256 threads, (p = t>>4, kd = t&15) ----
  if (t < 256) {
    const int p = t >> 4, kd = t & 15;
    const int idx = s_idx[p];
    const float salv = s_val[p];
    const float* __restrict__ xr = x + ((size_t)b * N + idx) * DIM;
    float a = b_lift[kd];
#pragma unroll 8
    for (int d = 0; d < DIM; ++d)
      a = fmaf((xr[d] - mu[d]) * __builtin_amdgcn_rcpf(sigma[d]), W_lift[d * KD + kd], a);
    a = fmaf((salv - mu[64]) * __builtin_amdgcn_rcpf(sigma[64]), W_lift[64 * KD + kd], a);
    a = fmaf(((float)idx * (1.f / (float)N) - mu[65]) * __builtin_amdgcn_rcpf(sigma[65]),
             W_lift[65 * KD + kd], a);
    lifted[p][kd] = a;
  }
  __syncthreads();

  // ---- project: 1024 threads; thread = (pg = t>>8, d2 = t&255), 4 points each ----
  const int d2 = t & 255, pg = t >> 8;
  const float2* __restrict__ Wp2 = (const float2*)W_proj;
  const float2 bp = ((const float2*)b_proj)[d2];
#pragma unroll
  for (int q = 0; q < 4; ++q) {
    const int p2 = pg * 4 + q;
    float2 o = bp;
#pragma unroll
    for (int c = 0; c < KD; ++c) {
      const float2 w = Wp2[c * 256 + d2];
      o.x = fmaf(lifted[p2][c], w.x, o.x);
      o.y = fmaf(lifted[p2][c], w.y, o.y);
    }
    ((float2*)(tokens + ((size_t)b * MP + p2) * DM))[d2] = o;
  }
}

extern "C" void kernel_launch(void* const* d_in, const int* in_sizes, int n_in,
                              void* d_out, int out_size, void* d_ws, size_t ws_size,
                              hipStream_t stream) {
  const float* x      = (const float*)d_in[0];
  const float* W1     = (const float*)d_in[1];
  const float* b1     = (const float*)d_in[2];
  // d_in[3] = w_e (unused by the reference outputs)
  const float* w_s    = (const float*)d_in[4];
  const float* W_lift = (const float*)d_in[5];
  const float* b_lift = (const float*)d_in[6];
  const float* W_proj = (const float*)d_in[7];
  const float* b_proj = (const float*)d_in[8];
  const float* mu     = (const float*)d_in[9];
  const float* sigma  = (const float*)d_in[10];

  float* tokens = (float*)d_out;                       // [B, MP, DM]
  float* ystar  = (float*)d_out + (size_t)B * MP * DM; // [B, N] (saliency staged here)

  _Float16* Wt_hi = (_Float16*)d_ws;                   // 4096 halfs (8 KB)
  _Float16* Wt_lo = Wt_hi + 4096;                      // 4096 halfs (8 KB)

  k_prepw<<<16, 256, 0, stream>>>(W1, Wt_hi, Wt_lo);
  k_saliency<<<GRID_SAL, 256, 0, stream>>>(x, Wt_hi, Wt_lo, b1, w_s, ystar);
  k_rowtok<<<B, 1024, 0, stream>>>(ystar, x, W_lift, b_lift,
                                   W_proj, b_proj, mu, sigma, tokens);
}

// Round 13
// 87.344 us; speedup vs baseline: 1.1811x; 1.1811x over previous
//
#include <hip/hip_runtime.h>
#include <math.h>

#define B 32
#define N 16384
#define DIM 64
#define HID 64
#define KD 16
#define DM 512
#define MP 16

#define GRID_SAL 2048   // ISOLATED CHANGE vs r11: 8 blocks/CU nominal (TLP)
#define ITERS 4         // 2048 * 4 * 64 rows = 524288 = B*N

typedef __attribute__((ext_vector_type(8))) _Float16 f16x8;
typedef __attribute__((ext_vector_type(2))) __fp16 fph2;   // cvt_pkrtz return type
typedef __attribute__((ext_vector_type(4))) float f32x4;

// tanh via exp + RAW v_rcp (no -ffast-math: '/' would emit the IEEE div sequence).
__device__ __forceinline__ float fast_tanh(float a) {
  const float e = __expf(2.f * a);
  return 1.f - 2.f * __builtin_amdgcn_rcpf(e + 1.f);
}

// ---------- Kernel 0: one-time W1 -> transposed fp16 hi/lo split (Wt[col][k]) ----------
__global__ __launch_bounds__(256) void k_prepw(
    const float* __restrict__ W1, _Float16* __restrict__ Wt_hi, _Float16* __restrict__ Wt_lo) {
  const int i = blockIdx.x * 256 + threadIdx.x;   // < 4096
  const int col = i >> 6, k = i & 63;
  const float v = W1[k * HID + col];
  const _Float16 h = (_Float16)v;
  Wt_hi[i] = h;
  Wt_lo[i] = (_Float16)(v - (float)h);
}

// ---------- Kernel 1: saliency, persistent + pipelined, fp16x3 MFMA, W in registers ----------
__global__ __launch_bounds__(256) void k_saliency(
    const float* __restrict__ x, const _Float16* __restrict__ Wt_hi,
    const _Float16* __restrict__ Wt_lo, const float* __restrict__ b1,
    const float* __restrict__ w_s, float* __restrict__ sal) {
  const int t = threadIdx.x;
  const int lane = t & 63, wid = t >> 6;
  const int c16 = lane & 15, kq = lane >> 4;
  const int wbase = c16 * 64 + kq * 8;            // Wt elem base for this lane

  // Hoist ALL W fragments: WH/WL[ct*2+kc], tile-invariant, 64 VGPR total.
  f16x8 WH[8], WL[8];
#pragma unroll
  for (int ct = 0; ct < 4; ++ct)
#pragma unroll
    for (int kc = 0; kc < 2; ++kc) {
      const int off = ct * 1024 + kc * 32 + wbase;
      WH[ct * 2 + kc] = *(const f16x8*)(Wt_hi + off);
      WL[ct * 2 + kc] = *(const f16x8*)(Wt_lo + off);
    }

#define PKSPLIT(va, vb, HW, LW) {                                                  \
    const fph2 h_ = __builtin_amdgcn_cvt_pkrtz((va), (vb));                        \
    const fph2 l_ = __builtin_amdgcn_cvt_pkrtz((va) - (float)h_[0],                \
                                               (vb) - (float)h_[1]);               \
    HW = __builtin_bit_cast(unsigned, h_);                                         \
    LW = __builtin_bit_cast(unsigned, l_); }

#define SAL_LOADS(b0, b1_, b2, b3, it_) {                                          \
    const size_t row_ = ((size_t)(it_) * GRID_SAL + blockIdx.x) * 64 + wid * 16 + c16; \
    const float* __restrict__ p_ = x + row_ * DIM + kq * 8;                        \
    b0 = *(const float4*)(p_);       b1_ = *(const float4*)(p_ + 4);               \
    b2 = *(const float4*)(p_ + 32);  b3 = *(const float4*)(p_ + 36); }

#define SAL_COMPUTE(b0, b1_, b2, b3, it_) {                                        \
    f32x4 a0 = (f32x4)0.f, a1 = (f32x4)0.f, a2 = (f32x4)0.f, a3 = (f32x4)0.f;      \
    { /* kc = 0 */                                                                 \
      uint4 H, L;                                                                  \
      PKSPLIT(b0.x, b0.y, H.x, L.x); PKSPLIT(b0.z, b0.w, H.y, L.y);                \
      PKSPLIT(b1_.x, b1_.y, H.z, L.z); PKSPLIT(b1_.z, b1_.w, H.w, L.w);            \
      const f16x8 bh = __builtin_bit_cast(f16x8, H);                               \
      const f16x8 bl = __builtin_bit_cast(f16x8, L);                               \
      a0 = __builtin_amdgcn_mfma_f32_16x16x32_f16(WH[0], bh, a0, 0, 0, 0);         \
      a1 = __builtin_amdgcn_mfma_f32_16x16x32_f16(WH[2], bh, a1, 0, 0, 0);         \
      a2 = __builtin_amdgcn_mfma_f32_16x16x32_f16(WH[4], bh, a2, 0, 0, 0);         \
      a3 = __builtin_amdgcn_mfma_f32_16x16x32_f16(WH[6], bh, a3, 0, 0, 0);         \
      a0 = __builtin_amdgcn_mfma_f32_16x16x32_f16(WL[0], bh, a0, 0, 0, 0);         \
      a1 = __builtin_amdgcn_mfma_f32_16x16x32_f16(WL[2], bh, a1, 0, 0, 0);         \
      a2 = __builtin_amdgcn_mfma_f32_16x16x32_f16(WL[4], bh, a2, 0, 0, 0);         \
      a3 = __builtin_amdgcn_mfma_f32_16x16x32_f16(WL[6], bh, a3, 0, 0, 0);         \
      a0 = __builtin_amdgcn_mfma_f32_16x16x32_f16(WH[0], bl, a0, 0, 0, 0);         \
      a1 = __builtin_amdgcn_mfma_f32_16x16x32_f16(WH[2], bl, a1, 0, 0, 0);         \
      a2 = __builtin_amdgcn_mfma_f32_16x16x32_f16(WH[4], bl, a2, 0, 0, 0);         \
      a3 = __builtin_amdgcn_mfma_f32_16x16x32_f16(WH[6], bl, a3, 0, 0, 0);         \
    }                                                                              \
    { /* kc = 1 */                                                                 \
      uint4 H, L;                                                                  \
      PKSPLIT(b2.x, b2.y, H.x, L.x); PKSPLIT(b2.z, b2.w, H.y, L.y);                \
      PKSPLIT(b3.x, b3.y, H.z, L.z); PKSPLIT(b3.z, b3.w, H.w, L.w);                \
      const f16x8 bh = __builtin_bit_cast(f16x8, H);                               \
      const f16x8 bl = __builtin_bit_cast(f16x8, L);                               \
      a0 = __builtin_amdgcn_mfma_f32_16x16x32_f16(WH[1], bh, a0, 0, 0, 0);         \
      a1 = __builtin_amdgcn_mfma_f32_16x16x32_f16(WH[3], bh, a1, 0, 0, 0);         \
      a2 = __builtin_amdgcn_mfma_f32_16x16x32_f16(WH[5], bh, a2, 0, 0, 0);         \
      a3 = __builtin_amdgcn_mfma_f32_16x16x32_f16(WH[7], bh, a3, 0, 0, 0);         \
      a0 = __builtin_amdgcn_mfma_f32_16x16x32_f16(WL[1], bh, a0, 0, 0, 0);         \
      a1 = __builtin_amdgcn_mfma_f32_16x16x32_f16(WL[3], bh, a1, 0, 0, 0);         \
      a2 = __builtin_amdgcn_mfma_f32_16x16x32_f16(WL[5], bh, a2, 0, 0, 0);         \
      a3 = __builtin_amdgcn_mfma_f32_16x16x32_f16(WL[7], bh, a3, 0, 0, 0);         \
      a0 = __builtin_amdgcn_mfma_f32_16x16x32_f16(WH[1], bl, a0, 0, 0, 0);         \
      a1 = __builtin_amdgcn_mfma_f32_16x16x32_f16(WH[3], bl, a1, 0, 0, 0);         \
      a2 = __builtin_amdgcn_mfma_f32_16x16x32_f16(WH[5], bl, a2, 0, 0, 0);         \
      a3 = __builtin_amdgcn_mfma_f32_16x16x32_f16(WH[7], bl, a3, 0, 0, 0);         \
    }                                                                              \
    float s = 0.f;                                                                 \
    { const f32x4 wv = *(const f32x4*)(w_s + kq * 4);                              \
      const f32x4 bv = *(const f32x4*)(b1 + kq * 4);                               \
      s = fmaf(wv[0], fast_tanh(a0[0] + bv[0]), s);                                \
      s = fmaf(wv[1], fast_tanh(a0[1] + bv[1]), s);                                \
      s = fmaf(wv[2], fast_tanh(a0[2] + bv[2]), s);                                \
      s = fmaf(wv[3], fast_tanh(a0[3] + bv[3]), s); }                              \
    { const f32x4 wv = *(const f32x4*)(w_s + 16 + kq * 4);                         \
      const f32x4 bv = *(const f32x4*)(b1 + 16 + kq * 4);                          \
      s = fmaf(wv[0], fast_tanh(a1[0] + bv[0]), s);                                \
      s = fmaf(wv[1], fast_tanh(a1[1] + bv[1]), s);                                \
      s = fmaf(wv[2], fast_tanh(a1[2] + bv[2]), s);                                \
      s = fmaf(wv[3], fast_tanh(a1[3] + bv[3]), s); }                              \
    { const f32x4 wv = *(const f32x4*)(w_s + 32 + kq * 4);                         \
      const f32x4 bv = *(const f32x4*)(b1 + 32 + kq * 4);                          \
      s = fmaf(wv[0], fast_tanh(a2[0] + bv[0]), s);                                \
      s = fmaf(wv[1], fast_tanh(a2[1] + bv[1]), s);                                \
      s = fmaf(wv[2], fast_tanh(a2[2] + bv[2]), s);                                \
      s = fmaf(wv[3], fast_tanh(a2[3] + bv[3]), s); }                              \
    { const f32x4 wv = *(const f32x4*)(w_s + 48 + kq * 4);                         \
      const f32x4 bv = *(const f32x4*)(b1 + 48 + kq * 4);                          \
      s = fmaf(wv[0], fast_tanh(a3[0] + bv[0]), s);                                \
      s = fmaf(wv[1], fast_tanh(a3[1] + bv[1]), s);                                \
      s = fmaf(wv[2], fast_tanh(a3[2] + bv[2]), s);                                \
      s = fmaf(wv[3], fast_tanh(a3[3] + bv[3]), s); }                              \
    s += __shfl_xor(s, 16);                                                        \
    s += __shfl_xor(s, 32);                                                        \
    if (lane < 16) {                                                               \
      const size_t sr_ = ((size_t)(it_) * GRID_SAL + blockIdx.x) * 64 + wid * 16 + lane; \
      const float z_ = __expf(-fabsf(s));                                          \
      sal[sr_] = fmaxf(s, 0.f) + __logf(1.f + z_);   /* softplus, no libm */       \
    } }

  float4 pA0, pA1, pA2, pA3;   // ping buffer
  float4 pB0, pB1, pB2, pB3;   // pong buffer

  SAL_LOADS(pA0, pA1, pA2, pA3, 0);
#pragma unroll 1
  for (int it2 = 0; it2 < ITERS; it2 += 2) {
    SAL_LOADS(pB0, pB1, pB2, pB3, it2 + 1);       // prefetch odd tile
    SAL_COMPUTE(pA0, pA1, pA2, pA3, it2);         // compute even tile
    if (it2 + 2 < ITERS) SAL_LOADS(pA0, pA1, pA2, pA3, it2 + 2);
    SAL_COMPUTE(pB0, pB1, pB2, pB3, it2 + 1);     // compute odd tile
  }
#undef SAL_LOADS
#undef SAL_COMPUTE
#undef PKSPLIT
}

// ---------- Kernel 2: per-chunk (2048 elems) online-softmax partials + top-16 ----------
// Indices stored WITHIN-ROW (0..N-1): chunk c covers row (c>>3), row-offset (c&7)*2048.
__global__ __launch_bounds__(256) void k_chunk(
    const float* __restrict__ sal, float* __restrict__ cmax, float* __restrict__ csum,
    float* __restrict__ cval, int* __restrict__ cidx) {
  __shared__ float sb[4], ss[4], wv[4];
  __shared__ int wi[4];
  const int t = threadIdx.x, c = blockIdx.x;
  const int rowoff = (c & 7) * 2048;
  const size_t gbase = (size_t)c * 2048;
  float v[8];
#pragma unroll
  for (int j = 0; j < 8; ++j) v[j] = sal[gbase + t + 256 * j];

  float m = v[0];
#pragma unroll
  for (int j = 1; j < 8; ++j) m = fmaxf(m, v[j]);
#pragma unroll
  for (int off = 1; off < 64; off <<= 1) m = fmaxf(m, __shfl_xor(m, off));
  if ((t & 63) == 0) sb[t >> 6] = m;
  __syncthreads();
  m = fmaxf(fmaxf(sb[0], sb[1]), fmaxf(sb[2], sb[3]));

  float se = 0.f;
#pragma unroll
  for (int j = 0; j < 8; ++j) se += __expf(v[j] - m);
#pragma unroll
  for (int off = 1; off < 64; off <<= 1) se += __shfl_xor(se, off);
  if ((t & 63) == 0) ss[t >> 6] = se;
  __syncthreads();
  if (t == 0) { cmax[c] = m; csum[c] = ss[0] + ss[1] + ss[2] + ss[3]; }

  // top-16 of chunk, (value desc, index asc), indices within-row
  for (int k = 0; k < MP; ++k) {
    float bv = v[0]; int bj = 0;
#pragma unroll
    for (int j = 1; j < 8; ++j)
      if (v[j] > bv) { bv = v[j]; bj = j; }
    int bi = rowoff + t + 256 * bj;
#pragma unroll
    for (int off = 1; off < 64; off <<= 1) {
      const float ov = __shfl_xor(bv, off);
      const int   oi = __shfl_xor(bi, off);
      if (ov > bv || (ov == bv && oi < bi)) { bv = ov; bi = oi; }
    }
    if ((t & 63) == 0) { wv[t >> 6] = bv; wi[t >> 6] = bi; }
    __syncthreads();
    float Bv = wv[0]; int Bi = wi[0];
#pragma unroll
    for (int w = 1; w < 4; ++w)
      if (wv[w] > Bv || (wv[w] == Bv && wi[w] < Bi)) { Bv = wv[w]; Bi = wi[w]; }
    if (t == 0) { cval[c * MP + k] = Bv; cidx[c * MP + k] = Bi; }
    const int relidx = Bi - rowoff;
#pragma unroll
    for (int jj = 0; jj < 8; ++jj)
      if (relidx == t + 256 * jj) v[jj] = -INFINITY;
    __syncthreads();
  }
}

// ---------- Kernel 3: y_star elementwise (row stats from chunk partials; b block-uniform) ----------
__global__ __launch_bounds__(256) void k_ystar(
    float* __restrict__ y, const float* __restrict__ cmax, const float* __restrict__ csum) {
  const int b = blockIdx.x >> 6;                // 64 blocks per row (16384/256) -> uniform
  const int gi = blockIdx.x * 256 + threadIdx.x;
  float mx = cmax[b * 8];
#pragma unroll
  for (int c = 1; c < 8; ++c) mx = fmaxf(mx, cmax[b * 8 + c]);
  float S = 0.f;
#pragma unroll
  for (int c = 0; c < 8; ++c) S += csum[b * 8 + c] * __expf(cmax[b * 8 + c] - mx);
  const float inv = __builtin_amdgcn_rcpf(S);
  const float v = y[gi];
  const float sig = __builtin_amdgcn_rcpf(1.f + __expf(-v));
  y[gi] = fmaf(0.5f, sig, 4.f * __expf(v - mx) * inv);
}

// ---------- Kernel 4: merge top-16 + gather + lift + project, one block per row ----------
__global__ __launch_bounds__(256) void k_toptokens(
    const float* __restrict__ cval, const int* __restrict__ cidx,
    const float* __restrict__ x,
    const float* __restrict__ W_lift, const float* __restrict__ b_lift,
    const float* __restrict__ W_proj, const float* __restrict__ b_proj,
    const float* __restrict__ mu, const float* __restrict__ sigma,
    float* __restrict__ tokens) {
  __shared__ float wv[4];
  __shared__ int wi[4];
  __shared__ float s_val[MP];
  __shared__ int s_idx[MP];
  __shared__ float lifted[MP][KD + 1];
  const int b = blockIdx.x, t = threadIdx.x;

  // merge 128 candidates -> global top-16 (value desc, index asc)
  float v = -INFINITY; int i = 0x7fffffff;
  if (t < 128) { v = cval[b * 128 + t]; i = cidx[b * 128 + t]; }
  for (int k = 0; k < MP; ++k) {
    float bv = v; int bi = i;
#pragma unroll
    for (int off = 1; off < 64; off <<= 1) {
      const float ov = __shfl_xor(bv, off);
      const int   oi = __shfl_xor(bi, off);
      if (ov > bv || (ov == bv && oi < bi)) { bv = ov; bi = oi; }
    }
    if ((t & 63) == 0) { wv[t >> 6] = bv; wi[t >> 6] = bi; }
    __syncthreads();
    float Bv = wv[0]; int Bi = wi[0];
#pragma unroll
    for (int w = 1; w < 4; ++w)
      if (wv[w] > Bv || (wv[w] == Bv && wi[w] < Bi)) { Bv = wv[w]; Bi = wi[w]; }
    if (t == 0) { s_val[k] = Bv; s_idx[k] = Bi; }
    if (i == Bi) v = -INFINITY;
    __syncthreads();
  }

  // lift: thread (p = t>>4, kd = t&15) computes lifted[p][kd]; 1/sigma via v_rcp
  const int p = t >> 4, kd = t & 15;
  const int idx = s_idx[p];
  const float salv = s_val[p];
  const float* __restrict__ xr = x + ((size_t)b * N + idx) * DIM;
  float a = b_lift[kd];
#pragma unroll 8
  for (int d = 0; d < DIM; ++d)
    a = fmaf((xr[d] - mu[d]) * __builtin_amdgcn_rcpf(sigma[d]), W_lift[d * KD + kd], a);
  a = fmaf((salv - mu[64]) * __builtin_amdgcn_rcpf(sigma[64]), W_lift[64 * KD + kd], a);
  a = fmaf(((float)idx / (float)N - mu[65]) * __builtin_amdgcn_rcpf(sigma[65]),
           W_lift[65 * KD + kd], a);
  lifted[p][kd] = a;
  __syncthreads();

  // project: 16 points x 512 dims; thread t does float2 of each point
  const float2* __restrict__ Wp2 = (const float2*)W_proj;
  const float2 bp = ((const float2*)b_proj)[t];
#pragma unroll 1
  for (int p2 = 0; p2 < MP; ++p2) {
    float2 o = bp;
#pragma unroll
    for (int c = 0; c < KD; ++c) {
      const float2 w = Wp2[c * 256 + t];
      o.x = fmaf(lifted[p2][c], w.x, o.x);
      o.y = fmaf(lifted[p2][c], w.y, o.y);
    }
    ((float2*)(tokens + ((size_t)b * MP + p2) * DM))[t] = o;
  }
}

extern "C" void kernel_launch(void* const* d_in, const int* in_sizes, int n_in,
                              void* d_out, int out_size, void* d_ws, size_t ws_size,
                              hipStream_t stream) {
  const float* x      = (const float*)d_in[0];
  const float* W1     = (const float*)d_in[1];
  const float* b1     = (const float*)d_in[2];
  // d_in[3] = w_e (unused by the reference outputs)
  const float* w_s    = (const float*)d_in[4];
  const float* W_lift = (const float*)d_in[5];
  const float* b_lift = (const float*)d_in[6];
  const float* W_proj = (const float*)d_in[7];
  const float* b_proj = (const float*)d_in[8];
  const float* mu     = (const float*)d_in[9];
  const float* sigma  = (const float*)d_in[10];

  float* tokens = (float*)d_out;                       // [B, MP, DM]
  float* ystar  = (float*)d_out + (size_t)B * MP * DM; // [B, N] (saliency staged here)

  // workspace layout (floats)
  float* cmax    = (float*)d_ws + 1024;        // 256
  float* csum    = (float*)d_ws + 1280;        // 256
  float* cval    = (float*)d_ws + 1600;        // 4096
  int*   cidx    = (int*)d_ws + 5696;          // 4096 -> ends at float 9792
  _Float16* Wt_hi = (_Float16*)((float*)d_ws + 9792);   // 4096 halfs (8 KB)
  _Float16* Wt_lo = Wt_hi + 4096;                       // 4096 halfs (8 KB)

  k_prepw<<<16, 256, 0, stream>>>(W1, Wt_hi, Wt_lo);
  k_saliency<<<GRID_SAL, 256, 0, stream>>>(x, Wt_hi, Wt_lo, b1, w_s, ystar);
  k_chunk<<<(B * N) / 2048, 256, 0, stream>>>(ystar, cmax, csum, cval, cidx);
  k_ystar<<<(B * N) / 256, 256, 0, stream>>>(ystar, cmax, csum);
  k_toptokens<<<B, 256, 0, stream>>>(cval, cidx, x, W_lift, b_lift,
                                     W_proj, b_proj, mu, sigma, tokens);
}

// Round 14
// 69.491 us; speedup vs baseline: 1.4845x; 1.2569x over previous
//
#include <hip/hip_runtime.h>
#include <math.h>

#define B 32
#define N 16384
#define DIM 64
#define HID 64
#define KD 16
#define DM 512
#define MP 16

#define GRID_SAL 1024   // reverted: 4 blocks/CU (r13 showed 2048 hurts)
#define ITERS 8         // 1024 * 8 * 64 rows = 524288 = B*N

typedef __attribute__((ext_vector_type(8))) _Float16 f16x8;
typedef __attribute__((ext_vector_type(2))) __fp16 fph2;   // cvt_pkrtz return type
typedef __attribute__((ext_vector_type(4))) float f32x4;

// tanh via exp + RAW v_rcp (no -ffast-math: '/' would emit the IEEE div sequence).
__device__ __forceinline__ float fast_tanh(float a) {
  const float e = __expf(2.f * a);
  return 1.f - 2.f * __builtin_amdgcn_rcpf(e + 1.f);
}

// ---------- Kernel 1: saliency; W1 converted in-block (LDS) then held in registers ----------
__global__ __launch_bounds__(256) void k_saliency(
    const float* __restrict__ x, const float* __restrict__ W1,
    const float* __restrict__ b1, const float* __restrict__ w_s,
    float* __restrict__ sal) {
  const int t = threadIdx.x;
  const int lane = t & 63, wid = t >> 6;
  const int c16 = lane & 15, kq = lane >> 4;

  // ---- prologue: W1[k][col] -> LDS [col][72-padded k] fp16 hi/lo, then fragments ----
  __shared__ __align__(16) _Float16 lWh[64 * 72];   // 9216 B
  __shared__ __align__(16) _Float16 lWl[64 * 72];   // 9216 B
#pragma unroll
  for (int j = 0; j < 16; ++j) {
    const int i = t + 256 * j;            // coalesced read of 4096 floats
    const int k = i >> 6, col = i & 63;
    const float v = W1[i];
    const _Float16 h = (_Float16)v;
    lWh[col * 72 + k] = h;
    lWl[col * 72 + k] = (_Float16)(v - (float)h);
  }
  __syncthreads();

  f16x8 WH[8], WL[8];                     // tile-invariant, 64 VGPR
#pragma unroll
  for (int ct = 0; ct < 4; ++ct)
#pragma unroll
    for (int kc = 0; kc < 2; ++kc) {
      const int off = (ct * 16 + c16) * 72 + kc * 32 + kq * 8;   // byte off %16 == 0
      WH[ct * 2 + kc] = *(const f16x8*)(lWh + off);
      WL[ct * 2 + kc] = *(const f16x8*)(lWl + off);
    }

#define PKSPLIT(va, vb, HW, LW) {                                                  \
    const fph2 h_ = __builtin_amdgcn_cvt_pkrtz((va), (vb));                        \
    const fph2 l_ = __builtin_amdgcn_cvt_pkrtz((va) - (float)h_[0],                \
                                               (vb) - (float)h_[1]);               \
    HW = __builtin_bit_cast(unsigned, h_);                                         \
    LW = __builtin_bit_cast(unsigned, l_); }

#define SAL_LOADS(b0, b1_, b2, b3, it_) {                                          \
    const size_t row_ = ((size_t)(it_) * GRID_SAL + blockIdx.x) * 64 + wid * 16 + c16; \
    const float* __restrict__ p_ = x + row_ * DIM + kq * 8;                        \
    b0 = *(const float4*)(p_);       b1_ = *(const float4*)(p_ + 4);               \
    b2 = *(const float4*)(p_ + 32);  b3 = *(const float4*)(p_ + 36); }

#define SAL_COMPUTE(b0, b1_, b2, b3, it_) {                                        \
    f32x4 a0 = (f32x4)0.f, a1 = (f32x4)0.f, a2 = (f32x4)0.f, a3 = (f32x4)0.f;      \
    { /* kc = 0 */                                                                 \
      uint4 H, L;                                                                  \
      PKSPLIT(b0.x, b0.y, H.x, L.x); PKSPLIT(b0.z, b0.w, H.y, L.y);                \
      PKSPLIT(b1_.x, b1_.y, H.z, L.z); PKSPLIT(b1_.z, b1_.w, H.w, L.w);            \
      const f16x8 bh = __builtin_bit_cast(f16x8, H);                               \
      const f16x8 bl = __builtin_bit_cast(f16x8, L);                               \
      a0 = __builtin_amdgcn_mfma_f32_16x16x32_f16(WH[0], bh, a0, 0, 0, 0);         \
      a1 = __builtin_amdgcn_mfma_f32_16x16x32_f16(WH[2], bh, a1, 0, 0, 0);         \
      a2 = __builtin_amdgcn_mfma_f32_16x16x32_f16(WH[4], bh, a2, 0, 0, 0);         \
      a3 = __builtin_amdgcn_mfma_f32_16x16x32_f16(WH[6], bh, a3, 0, 0, 0);         \
      a0 = __builtin_amdgcn_mfma_f32_16x16x32_f16(WL[0], bh, a0, 0, 0, 0);         \
      a1 = __builtin_amdgcn_mfma_f32_16x16x32_f16(WL[2], bh, a1, 0, 0, 0);         \
      a2 = __builtin_amdgcn_mfma_f32_16x16x32_f16(WL[4], bh, a2, 0, 0, 0);         \
      a3 = __builtin_amdgcn_mfma_f32_16x16x32_f16(WL[6], bh, a3, 0, 0, 0);         \
      a0 = __builtin_amdgcn_mfma_f32_16x16x32_f16(WH[0], bl, a0, 0, 0, 0);         \
      a1 = __builtin_amdgcn_mfma_f32_16x16x32_f16(WH[2], bl, a1, 0, 0, 0);         \
      a2 = __builtin_amdgcn_mfma_f32_16x16x32_f16(WH[4], bl, a2, 0, 0, 0);         \
      a3 = __builtin_amdgcn_mfma_f32_16x16x32_f16(WH[6], bl, a3, 0, 0, 0);         \
    }                                                                              \
    { /* kc = 1 */                                                                 \
      uint4 H, L;                                                                  \
      PKSPLIT(b2.x, b2.y, H.x, L.x); PKSPLIT(b2.z, b2.w, H.y, L.y);                \
      PKSPLIT(b3.x, b3.y, H.z, L.z); PKSPLIT(b3.z, b3.w, H.w, L.w);                \
      const f16x8 bh = __builtin_bit_cast(f16x8, H);                               \
      const f16x8 bl = __builtin_bit_cast(f16x8, L);                               \
      a0 = __builtin_amdgcn_mfma_f32_16x16x32_f16(WH[1], bh, a0, 0, 0, 0);         \
      a1 = __builtin_amdgcn_mfma_f32_16x16x32_f16(WH[3], bh, a1, 0, 0, 0);         \
      a2 = __builtin_amdgcn_mfma_f32_16x16x32_f16(WH[5], bh, a2, 0, 0, 0);         \
      a3 = __builtin_amdgcn_mfma_f32_16x16x32_f16(WH[7], bh, a3, 0, 0, 0);         \
      a0 = __builtin_amdgcn_mfma_f32_16x16x32_f16(WL[1], bh, a0, 0, 0, 0);         \
      a1 = __builtin_amdgcn_mfma_f32_16x16x32_f16(WL[3], bh, a1, 0, 0, 0);         \
      a2 = __builtin_amdgcn_mfma_f32_16x16x32_f16(WL[5], bh, a2, 0, 0, 0);         \
      a3 = __builtin_amdgcn_mfma_f32_16x16x32_f16(WL[7], bh, a3, 0, 0, 0);         \
      a0 = __builtin_amdgcn_mfma_f32_16x16x32_f16(WH[1], bl, a0, 0, 0, 0);         \
      a1 = __builtin_amdgcn_mfma_f32_16x16x32_f16(WH[3], bl, a1, 0, 0, 0);         \
      a2 = __builtin_amdgcn_mfma_f32_16x16x32_f16(WH[5], bl, a2, 0, 0, 0);         \
      a3 = __builtin_amdgcn_mfma_f32_16x16x32_f16(WH[7], bl, a3, 0, 0, 0);         \
    }                                                                              \
    float s = 0.f;                                                                 \
    { const f32x4 wv = *(const f32x4*)(w_s + kq * 4);                              \
      const f32x4 bv = *(const f32x4*)(b1 + kq * 4);                               \
      s = fmaf(wv[0], fast_tanh(a0[0] + bv[0]), s);                                \
      s = fmaf(wv[1], fast_tanh(a0[1] + bv[1]), s);                                \
      s = fmaf(wv[2], fast_tanh(a0[2] + bv[2]), s);                                \
      s = fmaf(wv[3], fast_tanh(a0[3] + bv[3]), s); }                              \
    { const f32x4 wv = *(const f32x4*)(w_s + 16 + kq * 4);                         \
      const f32x4 bv = *(const f32x4*)(b1 + 16 + kq * 4);                          \
      s = fmaf(wv[0], fast_tanh(a1[0] + bv[0]), s);                                \
      s = fmaf(wv[1], fast_tanh(a1[1] + bv[1]), s);                                \
      s = fmaf(wv[2], fast_tanh(a1[2] + bv[2]), s);                                \
      s = fmaf(wv[3], fast_tanh(a1[3] + bv[3]), s); }                              \
    { const f32x4 wv = *(const f32x4*)(w_s + 32 + kq * 4);                         \
      const f32x4 bv = *(const f32x4*)(b1 + 32 + kq * 4);                          \
      s = fmaf(wv[0], fast_tanh(a2[0] + bv[0]), s);                                \
      s = fmaf(wv[1], fast_tanh(a2[1] + bv[1]), s);                                \
      s = fmaf(wv[2], fast_tanh(a2[2] + bv[2]), s);                                \
      s = fmaf(wv[3], fast_tanh(a2[3] + bv[3]), s); }                              \
    { const f32x4 wv = *(const f32x4*)(w_s + 48 + kq * 4);                         \
      const f32x4 bv = *(const f32x4*)(b1 + 48 + kq * 4);                          \
      s = fmaf(wv[0], fast_tanh(a3[0] + bv[0]), s);                                \
      s = fmaf(wv[1], fast_tanh(a3[1] + bv[1]), s);                                \
      s = fmaf(wv[2], fast_tanh(a3[2] + bv[2]), s);                                \
      s = fmaf(wv[3], fast_tanh(a3[3] + bv[3]), s); }                              \
    s += __shfl_xor(s, 16);                                                        \
    s += __shfl_xor(s, 32);                                                        \
    if (lane < 16) {                                                               \
      const size_t sr_ = ((size_t)(it_) * GRID_SAL + blockIdx.x) * 64 + wid * 16 + lane; \
      const float z_ = __expf(-fabsf(s));                                          \
      sal[sr_] = fmaxf(s, 0.f) + __logf(1.f + z_);   /* softplus, no libm */       \
    } }

  float4 pA0, pA1, pA2, pA3;   // ping buffer
  float4 pB0, pB1, pB2, pB3;   // pong buffer

  SAL_LOADS(pA0, pA1, pA2, pA3, 0);
#pragma unroll 1
  for (int it2 = 0; it2 < ITERS; it2 += 2) {
    SAL_LOADS(pB0, pB1, pB2, pB3, it2 + 1);       // prefetch odd tile
    SAL_COMPUTE(pA0, pA1, pA2, pA3, it2);         // compute even tile
    if (it2 + 2 < ITERS) SAL_LOADS(pA0, pA1, pA2, pA3, it2 + 2);
    SAL_COMPUTE(pB0, pB1, pB2, pB3, it2 + 1);     // compute odd tile
  }
#undef SAL_LOADS
#undef SAL_COMPUTE
#undef PKSPLIT
}

// ---------- Kernel 2: per-chunk (2048 elems) online-softmax partials + top-16 ----------
// Indices stored WITHIN-ROW (0..N-1): chunk c covers row (c>>3), row-offset (c&7)*2048.
__global__ __launch_bounds__(256) void k_chunk(
    const float* __restrict__ sal, float* __restrict__ cmax, float* __restrict__ csum,
    float* __restrict__ cval, int* __restrict__ cidx) {
  __shared__ float sb[4], ss[4], wv[4];
  __shared__ int wi[4];
  const int t = threadIdx.x, c = blockIdx.x;
  const int rowoff = (c & 7) * 2048;
  const size_t gbase = (size_t)c * 2048;
  float v[8];
#pragma unroll
  for (int j = 0; j < 8; ++j) v[j] = sal[gbase + t + 256 * j];

  float m = v[0];
#pragma unroll
  for (int j = 1; j < 8; ++j) m = fmaxf(m, v[j]);
#pragma unroll
  for (int off = 1; off < 64; off <<= 1) m = fmaxf(m, __shfl_xor(m, off));
  if ((t & 63) == 0) sb[t >> 6] = m;
  __syncthreads();
  m = fmaxf(fmaxf(sb[0], sb[1]), fmaxf(sb[2], sb[3]));

  float se = 0.f;
#pragma unroll
  for (int j = 0; j < 8; ++j) se += __expf(v[j] - m);
#pragma unroll
  for (int off = 1; off < 64; off <<= 1) se += __shfl_xor(se, off);
  if ((t & 63) == 0) ss[t >> 6] = se;
  __syncthreads();
  if (t == 0) { cmax[c] = m; csum[c] = ss[0] + ss[1] + ss[2] + ss[3]; }

  // top-16 of chunk, (value desc, index asc), indices within-row
  for (int k = 0; k < MP; ++k) {
    float bv = v[0]; int bj = 0;
#pragma unroll
    for (int j = 1; j < 8; ++j)
      if (v[j] > bv) { bv = v[j]; bj = j; }
    int bi = rowoff + t + 256 * bj;
#pragma unroll
    for (int off = 1; off < 64; off <<= 1) {
      const float ov = __shfl_xor(bv, off);
      const int   oi = __shfl_xor(bi, off);
      if (ov > bv || (ov == bv && oi < bi)) { bv = ov; bi = oi; }
    }
    if ((t & 63) == 0) { wv[t >> 6] = bv; wi[t >> 6] = bi; }
    __syncthreads();
    float Bv = wv[0]; int Bi = wi[0];
#pragma unroll
    for (int w = 1; w < 4; ++w)
      if (wv[w] > Bv || (wv[w] == Bv && wi[w] < Bi)) { Bv = wv[w]; Bi = wi[w]; }
    if (t == 0) { cval[c * MP + k] = Bv; cidx[c * MP + k] = Bi; }
    const int relidx = Bi - rowoff;
#pragma unroll
    for (int jj = 0; jj < 8; ++jj)
      if (relidx == t + 256 * jj) v[jj] = -INFINITY;
    __syncthreads();
  }
}

// ---------- Kernel 3: heterogeneous final: blocks 0..31 = merge+lift+project; 32..2079 = y_star ----------
__global__ __launch_bounds__(256) void k_final(
    float* __restrict__ y, const float* __restrict__ cmax, const float* __restrict__ csum,
    const float* __restrict__ cval, const int* __restrict__ cidx,
    const float* __restrict__ x,
    const float* __restrict__ W_lift, const float* __restrict__ b_lift,
    const float* __restrict__ W_proj, const float* __restrict__ b_proj,
    const float* __restrict__ mu, const float* __restrict__ sigma,
    float* __restrict__ tokens) {
  const int t = threadIdx.x;

  if (blockIdx.x >= 32) {
    // ---------------- y_star role ----------------
    const int bid = blockIdx.x - 32;              // 0..2047
    const int b = bid >> 6;                       // 64 blocks per row
    const int gi = bid * 256 + t;
    float mx = cmax[b * 8];
#pragma unroll
    for (int c = 1; c < 8; ++c) mx = fmaxf(mx, cmax[b * 8 + c]);
    float S = 0.f;
#pragma unroll
    for (int c = 0; c < 8; ++c) S += csum[b * 8 + c] * __expf(cmax[b * 8 + c] - mx);
    const float inv = __builtin_amdgcn_rcpf(S);
    const float v = y[gi];
    const float sig = __builtin_amdgcn_rcpf(1.f + __expf(-v));
    y[gi] = fmaf(0.5f, sig, 4.f * __expf(v - mx) * inv);
    return;
  }

  // ---------------- merge + lift + project role ----------------
  __shared__ float wv[4];
  __shared__ int wi[4];
  __shared__ float s_val[MP];
  __shared__ int s_idx[MP];
  __shared__ float lifted[MP][KD + 1];
  const int b = blockIdx.x;

  // merge 128 candidates -> global top-16 (value desc, index asc)
  float v = -INFINITY; int i = 0x7fffffff;
  if (t < 128) { v = cval[b * 128 + t]; i = cidx[b * 128 + t]; }
  for (int k = 0; k < MP; ++k) {
    float bv = v; int bi = i;
#pragma unroll
    for (int off = 1; off < 64; off <<= 1) {
      const float ov = __shfl_xor(bv, off);
      const int   oi = __shfl_xor(bi, off);
      if (ov > bv || (ov == bv && oi < bi)) { bv = ov; bi = oi; }
    }
    if ((t & 63) == 0) { wv[t >> 6] = bv; wi[t >> 6] = bi; }
    __syncthreads();
    float Bv = wv[0]; int Bi = wi[0];
#pragma unroll
    for (int w = 1; w < 4; ++w)
      if (wv[w] > Bv || (wv[w] == Bv && wi[w] < Bi)) { Bv = wv[w]; Bi = wi[w]; }
    if (t == 0) { s_val[k] = Bv; s_idx[k] = Bi; }
    if (i == Bi) v = -INFINITY;
    __syncthreads();
  }

  // lift: thread (p = t>>4, kd = t&15) computes lifted[p][kd]; 1/sigma via v_rcp
  const int p = t >> 4, kd = t & 15;
  const int idx = s_idx[p];
  const float salv = s_val[p];
  const float* __restrict__ xr = x + ((size_t)b * N + idx) * DIM;
  float a = b_lift[kd];
#pragma unroll 8
  for (int d = 0; d < DIM; ++d)
    a = fmaf((xr[d] - mu[d]) * __builtin_amdgcn_rcpf(sigma[d]), W_lift[d * KD + kd], a);
  a = fmaf((salv - mu[64]) * __builtin_amdgcn_rcpf(sigma[64]), W_lift[64 * KD + kd], a);
  a = fmaf(((float)idx / (float)N - mu[65]) * __builtin_amdgcn_rcpf(sigma[65]),
           W_lift[65 * KD + kd], a);
  lifted[p][kd] = a;
  __syncthreads();

  // project: 16 points x 512 dims; thread t does float2 of each point
  const float2* __restrict__ Wp2 = (const float2*)W_proj;
  const float2 bp = ((const float2*)b_proj)[t];
#pragma unroll 1
  for (int p2 = 0; p2 < MP; ++p2) {
    float2 o = bp;
#pragma unroll
    for (int c = 0; c < KD; ++c) {
      const float2 w = Wp2[c * 256 + t];
      o.x = fmaf(lifted[p2][c], w.x, o.x);
      o.y = fmaf(lifted[p2][c], w.y, o.y);
    }
    ((float2*)(tokens + ((size_t)b * MP + p2) * DM))[t] = o;
  }
}

extern "C" void kernel_launch(void* const* d_in, const int* in_sizes, int n_in,
                              void* d_out, int out_size, void* d_ws, size_t ws_size,
                              hipStream_t stream) {
  const float* x      = (const float*)d_in[0];
  const float* W1     = (const float*)d_in[1];
  const float* b1     = (const float*)d_in[2];
  // d_in[3] = w_e (unused by the reference outputs)
  const float* w_s    = (const float*)d_in[4];
  const float* W_lift = (const float*)d_in[5];
  const float* b_lift = (const float*)d_in[6];
  const float* W_proj = (const float*)d_in[7];
  const float* b_proj = (const float*)d_in[8];
  const float* mu     = (const float*)d_in[9];
  const float* sigma  = (const float*)d_in[10];

  float* tokens = (float*)d_out;                       // [B, MP, DM]
  float* ystar  = (float*)d_out + (size_t)B * MP * DM; // [B, N] (saliency staged here)

  // workspace layout (floats)
  float* cmax    = (float*)d_ws + 1024;        // 256
  float* csum    = (float*)d_ws + 1280;        // 256
  float* cval    = (float*)d_ws + 1600;        // 4096
  int*   cidx    = (int*)d_ws + 5696;          // 4096

  k_saliency<<<GRID_SAL, 256, 0, stream>>>(x, W1, b1, w_s, ystar);
  k_chunk<<<(B * N) / 2048, 256, 0, stream>>>(ystar, cmax, csum, cval, cidx);
  k_final<<<2048 + 32, 256, 0, stream>>>(ystar, cmax, csum, cval, cidx, x,
                                         W_lift, b_lift, W_proj, b_proj,
                                         mu, sigma, tokens);
}